// Round 1
// baseline (624.329 us; speedup 1.0000x reference)
//
#include <hip/hip_runtime.h>
#include <hip/hip_bf16.h>

// GetAffs: seg [1,1,4096,4096] f32 (integer labels 0..63), output [8,4096,4096] f32.
// out[o][i][j] = (zeroext(seg)[i+ox][j+oy] == seg[i][j]) ? 1.0f : 0.0f
// OFFSETS = (-1,0),(0,-1),(-2,0),(0,-2),(-4,0),(0,-4),(-8,0),(0,-8)
// Pure memory-streaming: 512 MiB out + ~64 MiB in. float4 everywhere.

#define IMG_H 4096
#define IMG_W 4096

__device__ __forceinline__ float4 eq4(float4 a, float4 b) {
    return make_float4(a.x == b.x ? 1.0f : 0.0f,
                       a.y == b.y ? 1.0f : 0.0f,
                       a.z == b.z ? 1.0f : 0.0f,
                       a.w == b.w ? 1.0f : 0.0f);
}

__global__ __launch_bounds__(256) void GetAffs_83416854823610_kernel(
        const float* __restrict__ seg, float* __restrict__ out) {
    const int i  = blockIdx.y;                                   // row
    const int j  = (blockIdx.x * blockDim.x + threadIdx.x) * 4;  // first of 4 cols
    const float4 zero4 = make_float4(0.f, 0.f, 0.f, 0.f);

    const size_t rowbase = (size_t)i * IMG_W;
    const float4* rowc = (const float4*)(seg + rowbase);
    const int jq = j >> 2;

    // center 4 pixels
    const float4 c = rowc[jq];

    // horizontal window seg[i][j-8 .. j+3]; j % 4 == 0 so whole-vector
    // zeroing for j<4 / j<8 exactly matches per-element zero-extension.
    const float4 l1 = (j >= 4) ? rowc[jq - 1] : zero4;  // cols j-4..j-1
    const float4 l2 = (j >= 8) ? rowc[jq - 2] : zero4;  // cols j-8..j-5
    float w[12];
    w[0] = l2.x; w[1] = l2.y; w[2]  = l2.z; w[3]  = l2.w;
    w[4] = l1.x; w[5] = l1.y; w[6]  = l1.z; w[7]  = l1.w;
    w[8] = c.x;  w[9] = c.y;  w[10] = c.z;  w[11] = c.w;

    // vertical neighbors (rows i-1, i-2, i-4, i-8), zero row if OOB
    const float4 v1 = (i >= 1) ? *(const float4*)(seg + (size_t)(i - 1) * IMG_W + j) : zero4;
    const float4 v2 = (i >= 2) ? *(const float4*)(seg + (size_t)(i - 2) * IMG_W + j) : zero4;
    const float4 v4 = (i >= 4) ? *(const float4*)(seg + (size_t)(i - 4) * IMG_W + j) : zero4;
    const float4 v8 = (i >= 8) ? *(const float4*)(seg + (size_t)(i - 8) * IMG_W + j) : zero4;

    // horizontal neighbor vectors: lane k, dist d -> w[8 + k - d]
    const float4 h1 = make_float4(w[7], w[8], w[9],  w[10]);
    const float4 h2 = make_float4(w[6], w[7], w[8],  w[9]);
    const float4 h4 = make_float4(w[4], w[5], w[6],  w[7]);
    const float4 h8 = make_float4(w[0], w[1], w[2],  w[3]);

    const size_t HW = (size_t)IMG_H * IMG_W;
    const size_t base = rowbase + (size_t)j;
    *(float4*)(out + 0 * HW + base) = eq4(v1, c);  // (-1, 0)
    *(float4*)(out + 1 * HW + base) = eq4(h1, c);  // ( 0,-1)
    *(float4*)(out + 2 * HW + base) = eq4(v2, c);  // (-2, 0)
    *(float4*)(out + 3 * HW + base) = eq4(h2, c);  // ( 0,-2)
    *(float4*)(out + 4 * HW + base) = eq4(v4, c);  // (-4, 0)
    *(float4*)(out + 5 * HW + base) = eq4(h4, c);  // ( 0,-4)
    *(float4*)(out + 6 * HW + base) = eq4(v8, c);  // (-8, 0)
    *(float4*)(out + 7 * HW + base) = eq4(h8, c);  // ( 0,-8)
}

extern "C" void kernel_launch(void* const* d_in, const int* in_sizes, int n_in,
                              void* d_out, int out_size, void* d_ws, size_t ws_size,
                              hipStream_t stream) {
    const float* seg = (const float*)d_in[0];
    float* out = (float*)d_out;
    // 4096 cols / (4 per thread * 256 threads) = 4 blocks in x; one row per y.
    dim3 grid(IMG_W / (4 * 256), IMG_H);
    dim3 block(256);
    GetAffs_83416854823610_kernel<<<grid, block, 0, stream>>>(seg, out);
}

// Round 3
// 578.007 us; speedup vs baseline: 1.0801x; 1.0801x over previous
//
#include <hip/hip_runtime.h>
#include <hip/hip_bf16.h>

// GetAffs: seg [1,1,4096,4096] f32 (integer labels), out [8,4096,4096] f32.
// out[o][i][j] = (zeroext(seg)[i+ox][j+oy] == seg[i][j]) ? 1.0f : 0.0f
// OFFSETS: (-1,0),(0,-1),(-2,0),(0,-2),(-4,0),(0,-4),(-8,0),(0,-8)
//
// R2: same row-band register-ring scheme as R1; NT store now goes through a
// native ext_vector_type (the builtin rejects HIP_vector_type structs).

#define IMG_H 4096
#define IMG_W 4096
#define BAND  16

typedef float floatx4 __attribute__((ext_vector_type(4)));

__device__ __forceinline__ float4 ld4(const float* p) { return *(const float4*)p; }

__device__ __forceinline__ void st4_nt(float* p, float4 v) {
    floatx4 x = { v.x, v.y, v.z, v.w };
    __builtin_nontemporal_store(x, (floatx4*)p);
}

__device__ __forceinline__ float4 eq4(float4 a, float4 b) {
    return make_float4(a.x == b.x ? 1.0f : 0.0f,
                       a.y == b.y ? 1.0f : 0.0f,
                       a.z == b.z ? 1.0f : 0.0f,
                       a.w == b.w ? 1.0f : 0.0f);
}

__global__ __launch_bounds__(256) void GetAffs_83416854823610_kernel(
        const float* __restrict__ seg, float* __restrict__ out) {
    const int jq = blockIdx.x * 256 + threadIdx.x;  // float4 column group, 0..1023
    const int j  = jq << 2;                         // first of this thread's 4 cols
    const int i0 = blockIdx.y * BAND;               // first row of this band
    const float4 zero4 = make_float4(0.f, 0.f, 0.f, 0.f);

    // Ring: slot(row r) = (r - i0) & 7. Preload rows i0-8 .. i0-1 (zero if OOB).
    float4 hist[8];
#pragma unroll
    for (int k = 0; k < 8; ++k) {
        const int r = i0 - 8 + k;                   // slot = (r - i0) & 7 = k
        hist[k] = (r >= 0) ? ld4(seg + (size_t)r * IMG_W + j) : zero4;
    }

    const size_t HW = (size_t)IMG_H * IMG_W;

#pragma unroll
    for (int u = 0; u < BAND; ++u) {                // row i = i0 + u
        const int i = i0 + u;
        const float* row = seg + (size_t)i * IMG_W;
        const float4 c  = ld4(row + j);
        const float4 l1 = (j >= 4) ? ld4(row + j - 4) : zero4;  // cols j-4..j-1
        const float4 l2 = (j >= 8) ? ld4(row + j - 8) : zero4;  // cols j-8..j-5

        // vertical neighbors from the register ring (slots are compile-time)
        const float4 v1 = hist[(u + 7) & 7];        // row i-1
        const float4 v2 = hist[(u + 6) & 7];        // row i-2
        const float4 v4 = hist[(u + 4) & 7];        // row i-4
        const float4 v8 = hist[u & 7];              // row i-8

        // horizontal neighbors: element k of plane (0,-d) is seg[i][j+k-d]
        const float4 h1 = make_float4(l1.w, c.x, c.y, c.z);
        const float4 h2 = make_float4(l1.z, l1.w, c.x, c.y);
        const float4 h4 = l1;
        const float4 h8 = l2;

        const size_t base = (size_t)i * IMG_W + (size_t)j;
        st4_nt(out + 0 * HW + base, eq4(v1, c));    // (-1, 0)
        st4_nt(out + 1 * HW + base, eq4(h1, c));    // ( 0,-1)
        st4_nt(out + 2 * HW + base, eq4(v2, c));    // (-2, 0)
        st4_nt(out + 3 * HW + base, eq4(h2, c));    // ( 0,-2)
        st4_nt(out + 4 * HW + base, eq4(v4, c));    // (-4, 0)
        st4_nt(out + 5 * HW + base, eq4(h4, c));    // ( 0,-4)
        st4_nt(out + 6 * HW + base, eq4(v8, c));    // (-8, 0)
        st4_nt(out + 7 * HW + base, eq4(h8, c));    // ( 0,-8)

        hist[u & 7] = c;  // row i replaces row i-8 (already consumed as v8)
    }
}

extern "C" void kernel_launch(void* const* d_in, const int* in_sizes, int n_in,
                              void* d_out, int out_size, void* d_ws, size_t ws_size,
                              hipStream_t stream) {
    const float* seg = (const float*)d_in[0];
    float* out = (float*)d_out;
    // 1024 col-groups / 256 threads = 4 blocks in x; 4096/16 = 256 bands in y.
    dim3 grid((IMG_W / 4) / 256, IMG_H / BAND);
    dim3 block(256);
    GetAffs_83416854823610_kernel<<<grid, block, 0, stream>>>(seg, out);
}